// Round 1
// baseline (207.572 us; speedup 1.0000x reference)
//
#include <hip/hip_runtime.h>

#define N 10
#define D 1024
#define NREL 200

// ---------------- workspace layout (float offsets) ----------------
// q       : 0          (N*D)
// k       : 10240      (N*D)
// rgcn_acc: 20480      (N*D)   edge msgs + root accumulate here
// outv    : 30720      (N*D)   rgcn_acc + bias
// aggrel  : 40960      (D)     agg_row @ gcn_rel_w
// x2acc   : 41984      (N*D)   outv @ gcn_root_w
// agg     : 52224      (D)     sum of outv rows
// w_e     : 53248      (100)
// etype   : 53348      (100 ints)
#define OFF_Q       0
#define OFF_K       10240
#define OFF_RGCN    20480
#define OFF_OUTV    30720
#define OFF_AGGREL  40960
#define OFF_X2ACC   41984
#define OFF_AGG     52224
#define OFF_WE      53248
#define OFF_ETYPE   53348

// Y[r, :] += X[r, kb:kb+128] @ W[kb:kb+128, :]   (atomic partial over k-chunks)
// grid: (rows, 4 col-tiles, 8 k-chunks), block 256
__global__ void matvec_split(const float* __restrict__ X, const float* __restrict__ W,
                             float* __restrict__ Y) {
    int r  = blockIdx.x;
    int c  = blockIdx.y * 256 + threadIdx.x;
    int kb = blockIdx.z * 128;
    const float* x  = X + r * D + kb;
    const float* Wp = W + (size_t)kb * D + c;
    float acc = 0.f;
#pragma unroll 8
    for (int k = 0; k < 128; ++k) acc += x[k] * Wp[(size_t)k * D];
    atomicAdd(&Y[r * D + c], acc);
}

// single block, 256 threads: logits -> softmax -> etype -> per-(rel,dst) count -> w_e
__global__ void attn_edges(const float* __restrict__ q, const float* __restrict__ k,
                           const int* __restrict__ speaker,
                           float* __restrict__ w_e, int* __restrict__ etype_out) {
    __shared__ float logits[N * N];
    __shared__ float attn[N * N];
    __shared__ int   cnt[NREL * N];   // 2000 ints = 8 KB
    int tid  = threadIdx.x;
    int wave = tid >> 6, lane = tid & 63;

    // logits[i][j] = dot(q[i], k[j]) / sqrt(D)
    for (int p = wave; p < N * N; p += 4) {
        int i = p / N, j = p % N;
        float acc = 0.f;
        for (int t = lane; t < D; t += 64) acc += q[i * D + t] * k[j * D + t];
        for (int off = 32; off; off >>= 1) acc += __shfl_down(acc, off);
        if (lane == 0) logits[p] = acc * (1.0f / 32.0f);   // sqrt(1024) = 32
    }
    __syncthreads();

    if (tid < N) {                       // row softmax
        float m = -1e30f;
        for (int j = 0; j < N; ++j) m = fmaxf(m, logits[tid * N + j]);
        float s = 0.f, e[N];
        for (int j = 0; j < N; ++j) { e[j] = expf(logits[tid * N + j] - m); s += e[j]; }
        for (int j = 0; j < N; ++j) attn[tid * N + j] = e[j] / s;
    }
    for (int i = tid; i < NREL * N; i += 256) cnt[i] = 0;
    __syncthreads();

    if (tid < N * N) {                   // edge e = src*N + dst (row-major product order)
        int src = tid / N, dst = tid % N;
        int et  = 2 * (speaker[src] * N + speaker[dst]) + (src >= dst ? 1 : 0);
        etype_out[tid] = et;
        atomicAdd(&cnt[et * N + dst], 1);
    }
    __syncthreads();

    if (tid < N * N) {
        int dst = tid % N;
        w_e[tid] = attn[tid] / (float)cnt[etype_out[tid] * N + dst];
    }
}

// accum[dst, :] += w_e[e] * (X[src] @ rgcn_weight[etype[e]])
// grid: (100 edges, 8 k-chunks), block 256 threads x float4 cols
__global__ void edge_matvec(const float* __restrict__ X, const float* __restrict__ Wr,
                            const float* __restrict__ w_e, const int* __restrict__ etype,
                            float* __restrict__ accum) {
    int e   = blockIdx.x;
    int src = e / N, dst = e % N;
    int t   = etype[e];
    float we = w_e[e];
    const float* W = Wr + (size_t)t * D * D;
    const float* x = X + src * D;
    int c0 = threadIdx.x * 4;
    int kb = blockIdx.y * 128;
    float4 acc = make_float4(0.f, 0.f, 0.f, 0.f);
    for (int k = kb; k < kb + 128; ++k) {
        float  xv = x[k];
        float4 w4 = *reinterpret_cast<const float4*>(W + (size_t)k * D + c0);
        acc.x += xv * w4.x; acc.y += xv * w4.y; acc.z += xv * w4.z; acc.w += xv * w4.w;
    }
    float* o = accum + dst * D + c0;
    atomicAdd(o + 0, we * acc.x);
    atomicAdd(o + 1, we * acc.y);
    atomicAdd(o + 2, we * acc.z);
    atomicAdd(o + 3, we * acc.w);
}

// outv = rgcn_acc + bias        grid (10,4), block 256
__global__ void bias_out(const float* __restrict__ acc, const float* __restrict__ bias,
                         float* __restrict__ outv) {
    int r = blockIdx.x, c = blockIdx.y * 256 + threadIdx.x;
    outv[r * D + c] = acc[r * D + c] + bias[c];
}

// agg[c] = sum_r outv[r][c]     grid 4, block 256
__global__ void sum_rows(const float* __restrict__ outv, float* __restrict__ agg) {
    int c = blockIdx.x * 256 + threadIdx.x;
    float s = 0.f;
    for (int r = 0; r < N; ++r) s += outv[r * D + c];
    agg[c] = s;
}

// dout[r][c] = x2acc[r][c] + aggrel[c] + rel_b[c]  (c<1024);  dout[r][1024+c] = X[r][c]
// grid (10, 8), block 256
__global__ void final_concat(const float* __restrict__ x2acc, const float* __restrict__ aggrel,
                             const float* __restrict__ rel_b, const float* __restrict__ X,
                             float* __restrict__ dout) {
    int r = blockIdx.x, c = blockIdx.y * 256 + threadIdx.x;
    if (c < D) {
        dout[r * 2 * D + c] = x2acc[r * D + c] + aggrel[c] + rel_b[c];
    } else {
        dout[r * 2 * D + c] = X[r * D + (c - D)];
    }
}

extern "C" void kernel_launch(void* const* d_in, const int* in_sizes, int n_in,
                              void* d_out, int out_size, void* d_ws, size_t ws_size,
                              hipStream_t stream) {
    const float* X        = (const float*)d_in[0];
    const int*   speaker  = (const int*)  d_in[1];
    const float* Wq       = (const float*)d_in[2];
    const float* Wk       = (const float*)d_in[3];
    const float* Wrel     = (const float*)d_in[4];
    const float* Wroot    = (const float*)d_in[5];
    const float* bias     = (const float*)d_in[6];
    const float* gcn_rel_w = (const float*)d_in[7];
    const float* gcn_rel_b = (const float*)d_in[8];
    const float* gcn_root_w = (const float*)d_in[9];
    float* ws   = (float*)d_ws;
    float* dout = (float*)d_out;

    float* q      = ws + OFF_Q;
    float* kbuf   = ws + OFF_K;
    float* rgcn   = ws + OFF_RGCN;
    float* outv   = ws + OFF_OUTV;
    float* aggrel = ws + OFF_AGGREL;
    float* x2acc  = ws + OFF_X2ACC;
    float* agg    = ws + OFF_AGG;
    float* w_e    = ws + OFF_WE;
    int*   etype  = (int*)(ws + OFF_ETYPE);

    // zero the atomic accumulators (ws is NOT re-poisoned between replays; we re-zero every call)
    hipMemsetAsync(q,      0, 2 * N * D * sizeof(float), stream);            // q + k (contiguous)
    hipMemsetAsync(rgcn,   0, N * D * sizeof(float), stream);
    hipMemsetAsync(aggrel, 0, (D + N * D) * sizeof(float), stream);          // aggrel + x2acc (contiguous)

    dim3 blk(256);
    // q = X@Wq, k = X@Wk
    matvec_split<<<dim3(N, 4, 8), blk, 0, stream>>>(X, Wq, q);
    matvec_split<<<dim3(N, 4, 8), blk, 0, stream>>>(X, Wk, kbuf);

    // attn -> w_e, etype
    attn_edges<<<1, blk, 0, stream>>>(q, kbuf, speaker, w_e, etype);

    // RGCN edge messages (the big one: ~400 MB of relation-weight reads)
    edge_matvec<<<dim3(N * N, 8), blk, 0, stream>>>(X, Wrel, w_e, etype, rgcn);

    // += X @ rgcn_root
    matvec_split<<<dim3(N, 4, 8), blk, 0, stream>>>(X, Wroot, rgcn);

    // outv = rgcn + bias
    bias_out<<<dim3(N, 4), blk, 0, stream>>>(rgcn, bias, outv);

    // agg row (same for every dst: dense all-pairs sum aggregation)
    sum_rows<<<dim3(4), blk, 0, stream>>>(outv, agg);

    // aggrel = agg @ gcn_rel_w ; x2acc = outv @ gcn_root_w
    matvec_split<<<dim3(1, 4, 8), blk, 0, stream>>>(agg, gcn_rel_w, aggrel);
    matvec_split<<<dim3(N, 4, 8), blk, 0, stream>>>(outv, gcn_root_w, x2acc);

    // x2 + bias, concat with X
    final_concat<<<dim3(N, 8), blk, 0, stream>>>(x2acc, aggrel, gcn_rel_b, X, dout);
}

// Round 2
// 189.767 us; speedup vs baseline: 1.0938x; 1.0938x over previous
//
#include <hip/hip_runtime.h>

#define N 10
#define D 1024
#define NREL 200
#define KCH 16            // k-chunks in the big edge-matvec
#define KLEN 64           // D / KCH

// ---------------- workspace layout (float offsets) ----------------
// [q | k | rootacc | aggrel | x2acc] are atomic accumulators -> one contiguous memset
#define OFF_Q       0                      // N*D
#define OFF_K       (OFF_Q + N*D)          // N*D
#define OFF_ROOT    (OFF_K + N*D)          // N*D   X @ rgcn_root (atomic)
#define OFF_AGGREL  (OFF_ROOT + N*D)       // D     agg @ gcn_rel_w (atomic)
#define OFF_X2ACC   (OFF_AGGREL + D)       // N*D   outv @ gcn_root_w (atomic)
#define ZERO_FLOATS (OFF_X2ACC + N*D)      // everything above gets memset to 0
#define OFF_OUTV    ZERO_FLOATS            // N*D
#define OFF_AGG     (OFF_OUTV + N*D)       // D
#define OFF_WE      (OFF_AGG + D)          // 100
#define OFF_ETYPE   (OFF_WE + 128)         // 100 ints
#define OFF_EMPART  (OFF_ETYPE + 128)      // KCH*100*D floats (6.55 MB)

// ---- generic split matvec: Y[row] += X[row, kb:kb+128] @ W[kb:kb+128, :] ----
__device__ __forceinline__ void matvec_body(const float* __restrict__ x,
                                            const float* __restrict__ W,
                                            float* __restrict__ y,
                                            int c, int kb) {
    const float* Wp = W + (size_t)kb * D + c;
    const float* xp = x + kb;
    float acc = 0.f;
#pragma unroll 8
    for (int k = 0; k < 128; ++k) acc += xp[k] * Wp[(size_t)k * D];
    atomicAdd(&y[c], acc);
}

// q = X@Wq, k = X@Wk   grid (20, 4, 8) block 256
__global__ void qk_matvec(const float* __restrict__ X, const float* __restrict__ Wq,
                          const float* __restrict__ Wk, float* __restrict__ q,
                          float* __restrict__ kout) {
    int r   = blockIdx.x % N;
    int sel = blockIdx.x / N;
    const float* W = sel ? Wk : Wq;
    float*       Y = sel ? kout : q;
    matvec_body(X + r * D, W, Y + r * D, blockIdx.y * 256 + threadIdx.x, blockIdx.z * 128);
}

// rootacc[r] += X[r] @ Wroot   grid (10, 4, 8)
__global__ void root_matvec(const float* __restrict__ X, const float* __restrict__ Wroot,
                            float* __restrict__ rootacc) {
    int r = blockIdx.x;
    matvec_body(X + r * D, Wroot, rootacc + r * D, blockIdx.y * 256 + threadIdx.x,
                blockIdx.z * 128);
}

// rows 0..9: x2acc[r] += outv[r] @ gcn_root_w ; row 10: aggrel += agg @ gcn_rel_w
// grid (11, 4, 8)
__global__ void final_matvec(const float* __restrict__ outv, const float* __restrict__ agg,
                             const float* __restrict__ root_w, const float* __restrict__ rel_w,
                             float* __restrict__ x2acc, float* __restrict__ aggrel) {
    int r = blockIdx.x;
    const float* x = (r < N) ? outv + r * D : agg;
    const float* W = (r < N) ? root_w : rel_w;
    float*       y = (r < N) ? x2acc + r * D : aggrel;
    matvec_body(x, W, y, blockIdx.y * 256 + threadIdx.x, blockIdx.z * 128);
}

// single block: logits -> softmax -> etype -> per-(rel,dst) count -> w_e
__global__ void attn_edges(const float* __restrict__ q, const float* __restrict__ k,
                           const int* __restrict__ speaker,
                           float* __restrict__ w_e, int* __restrict__ etype_out) {
    __shared__ float logits[N * N];
    __shared__ float attn[N * N];
    __shared__ int   cnt[NREL * N];   // 8 KB
    int tid  = threadIdx.x;
    int wave = tid >> 6, lane = tid & 63;

    for (int p = wave; p < N * N; p += 4) {
        int i = p / N, j = p % N;
        float acc = 0.f;
        for (int t = lane; t < D; t += 64) acc += q[i * D + t] * k[j * D + t];
        for (int off = 32; off; off >>= 1) acc += __shfl_down(acc, off);
        if (lane == 0) logits[p] = acc * (1.0f / 32.0f);   // 1/sqrt(1024)
    }
    __syncthreads();

    if (tid < N) {
        float m = -1e30f;
        for (int j = 0; j < N; ++j) m = fmaxf(m, logits[tid * N + j]);
        float s = 0.f, e[N];
        for (int j = 0; j < N; ++j) { e[j] = expf(logits[tid * N + j] - m); s += e[j]; }
        for (int j = 0; j < N; ++j) attn[tid * N + j] = e[j] / s;
    }
    for (int i = tid; i < NREL * N; i += 256) cnt[i] = 0;
    __syncthreads();

    if (tid < N * N) {
        int src = tid / N, dst = tid % N;
        int et  = 2 * (speaker[src] * N + speaker[dst]) + (src >= dst ? 1 : 0);
        etype_out[tid] = et;
        atomicAdd(&cnt[et * N + dst], 1);
    }
    __syncthreads();

    if (tid < N * N) {
        int dst = tid % N;
        w_e[tid] = attn[tid] / (float)cnt[etype_out[tid] * N + dst];
    }
}

// THE BIG ONE: em_part[kc][e][:] = X[src, kc*64:(kc+1)*64] @ Wrel[etype[e]][kc*64:..., :]
// grid (100, 16), block 256 (each thread: 4 contiguous cols). Non-atomic partials.
__global__ void edge_matvec_part(const float* __restrict__ X, const float* __restrict__ Wr,
                                 const int* __restrict__ etype, float* __restrict__ em_part) {
    int e   = blockIdx.x;
    int kc  = blockIdx.y;
    int src = e / N;
    int t   = etype[e];
    const float* W = Wr + (size_t)t * D * D + (size_t)kc * KLEN * D;
    const float* x = X + src * D + kc * KLEN;
    int c0 = threadIdx.x * 4;
    float4 acc = make_float4(0.f, 0.f, 0.f, 0.f);
#pragma unroll 8
    for (int k = 0; k < KLEN; ++k) {
        float  xv = x[k];
        float4 w4 = *reinterpret_cast<const float4*>(W + (size_t)k * D + c0);
        acc.x += xv * w4.x; acc.y += xv * w4.y; acc.z += xv * w4.z; acc.w += xv * w4.w;
    }
    *reinterpret_cast<float4*>(em_part + ((size_t)(kc * (N * N) + e)) * D + c0) = acc;
}

// outv[dst] = sum_src w_e[src,dst] * sum_kc em_part[kc][src*N+dst] + rootacc[dst] + bias
// grid (10, 4), block 256
__global__ void combine(const float* __restrict__ em_part, const float* __restrict__ w_e,
                        const float* __restrict__ rootacc, const float* __restrict__ bias,
                        float* __restrict__ outv) {
    int dst = blockIdx.x;
    int c   = blockIdx.y * 256 + threadIdx.x;
    float s = 0.f;
    for (int src = 0; src < N; ++src) {
        int e = src * N + dst;
        float sum = 0.f;
#pragma unroll
        for (int kc = 0; kc < KCH; ++kc)
            sum += em_part[((size_t)(kc * (N * N) + e)) * D + c];
        s += w_e[e] * sum;
    }
    outv[dst * D + c] = s + rootacc[dst * D + c] + bias[c];
}

// agg[c] = sum_r outv[r][c]     grid 4, block 256
__global__ void sum_rows(const float* __restrict__ outv, float* __restrict__ agg) {
    int c = blockIdx.x * 256 + threadIdx.x;
    float s = 0.f;
#pragma unroll
    for (int r = 0; r < N; ++r) s += outv[r * D + c];
    agg[c] = s;
}

// dout[r][0:1024] = x2acc[r] + aggrel + rel_b ; dout[r][1024:2048] = X[r]
// grid (10, 8), block 256
__global__ void final_concat(const float* __restrict__ x2acc, const float* __restrict__ aggrel,
                             const float* __restrict__ rel_b, const float* __restrict__ X,
                             float* __restrict__ dout) {
    int r = blockIdx.x, c = blockIdx.y * 256 + threadIdx.x;
    if (c < D) dout[r * 2 * D + c] = x2acc[r * D + c] + aggrel[c] + rel_b[c];
    else       dout[r * 2 * D + c] = X[r * D + (c - D)];
}

extern "C" void kernel_launch(void* const* d_in, const int* in_sizes, int n_in,
                              void* d_out, int out_size, void* d_ws, size_t ws_size,
                              hipStream_t stream) {
    const float* X          = (const float*)d_in[0];
    const int*   speaker    = (const int*)  d_in[1];
    const float* Wq         = (const float*)d_in[2];
    const float* Wk         = (const float*)d_in[3];
    const float* Wrel       = (const float*)d_in[4];
    const float* Wroot      = (const float*)d_in[5];
    const float* bias       = (const float*)d_in[6];
    const float* gcn_rel_w  = (const float*)d_in[7];
    const float* gcn_rel_b  = (const float*)d_in[8];
    const float* gcn_root_w = (const float*)d_in[9];
    float* ws   = (float*)d_ws;
    float* dout = (float*)d_out;

    float* q       = ws + OFF_Q;
    float* kbuf    = ws + OFF_K;
    float* rootacc = ws + OFF_ROOT;
    float* aggrel  = ws + OFF_AGGREL;
    float* x2acc   = ws + OFF_X2ACC;
    float* outv    = ws + OFF_OUTV;
    float* agg     = ws + OFF_AGG;
    float* w_e     = ws + OFF_WE;
    int*   etype   = (int*)(ws + OFF_ETYPE);
    float* em_part = ws + OFF_EMPART;

    // one contiguous zero for all atomic accumulators (ws not re-poisoned between replays)
    hipMemsetAsync(ws, 0, ZERO_FLOATS * sizeof(float), stream);

    dim3 blk(256);
    qk_matvec<<<dim3(2 * N, 4, 8), blk, 0, stream>>>(X, Wq, Wk, q, kbuf);
    attn_edges<<<1, blk, 0, stream>>>(q, kbuf, speaker, w_e, etype);

    // the ~400 MB weight-gather: 1600 blocks, non-atomic partials
    edge_matvec_part<<<dim3(N * N, KCH), blk, 0, stream>>>(X, Wrel, etype, em_part);

    root_matvec<<<dim3(N, 4, 8), blk, 0, stream>>>(X, Wroot, rootacc);
    combine<<<dim3(N, 4), blk, 0, stream>>>(em_part, w_e, rootacc, bias, outv);
    sum_rows<<<dim3(4), blk, 0, stream>>>(outv, agg);
    final_matvec<<<dim3(N + 1, 4, 8), blk, 0, stream>>>(outv, agg, gcn_root_w, gcn_rel_w,
                                                        x2acc, aggrel);
    final_concat<<<dim3(N, 8), blk, 0, stream>>>(x2acc, aggrel, gcn_rel_b, X, dout);
}

// Round 3
// 148.524 us; speedup vs baseline: 1.3976x; 1.2777x over previous
//
#include <hip/hip_runtime.h>

#define N 10
#define D 1024
#define NREL 200
#define KCH 32            // k-chunks in the big edge-matvec
#define KLEN 32           // D / KCH

// ---------------- workspace layout (float offsets) ----------------
// [q | k | root | aggrel | x2acc | agg] are atomic accumulators -> one contiguous memset
#define OFF_Q       0                      // N*D
#define OFF_K       (OFF_Q + N*D)          // N*D
#define OFF_ROOT    (OFF_K + N*D)          // N*D
#define OFF_AGGREL  (OFF_ROOT + N*D)       // D
#define OFF_X2ACC   (OFF_AGGREL + D)       // N*D
#define OFF_AGG     (OFF_X2ACC + N*D)      // D
#define ZERO_FLOATS (OFF_AGG + D)
#define OFF_OUTV    ZERO_FLOATS            // N*D
#define OFF_WE      (OFF_OUTV + N*D)       // 100 (pad 128)
#define OFF_ETYPE   (OFF_WE + 128)         // 100 ints (pad 128)
#define OFF_EMPART  (OFF_ETYPE + 128)      // KCH*100*D floats (13.1 MB)

// ---- generic split matvec body: y[c] += x[kb:kb+128] . W[kb:kb+128, c] ----
__device__ __forceinline__ void matvec_body(const float* __restrict__ x,
                                            const float* __restrict__ W,
                                            float* __restrict__ y,
                                            int c, int kb) {
    const float* Wp = W + (size_t)kb * D + c;
    const float* xp = x + kb;
    float acc = 0.f;
#pragma unroll 8
    for (int k = 0; k < 128; ++k) acc += xp[k] * Wp[(size_t)k * D];
    atomicAdd(&y[c], acc);
}

// rows 0..9: q[r] += X[r]@Wq ; 10..19: k[r] += X[r]@Wk ; 20..29: root[r] += X[r]@Wroot
// grid (30, 4, 8), block 256
__global__ void pre_matvec(const float* __restrict__ X, const float* __restrict__ Wq,
                           const float* __restrict__ Wk, const float* __restrict__ Wroot,
                           float* __restrict__ q, float* __restrict__ kout,
                           float* __restrict__ rootacc) {
    int r   = blockIdx.x % N;
    int sel = blockIdx.x / N;
    const float* W = (sel == 0) ? Wq : (sel == 1) ? Wk : Wroot;
    float*       Y = (sel == 0) ? q  : (sel == 1) ? kout : rootacc;
    matvec_body(X + r * D, W, Y + r * D, blockIdx.y * 256 + threadIdx.x, blockIdx.z * 128);
}

// single block, 1024 threads: logits -> softmax -> etype -> per-(rel,dst) count -> w_e
__global__ void attn_edges(const float* __restrict__ q, const float* __restrict__ k,
                           const int* __restrict__ speaker,
                           float* __restrict__ w_e, int* __restrict__ etype_out) {
    __shared__ float logits[N * N];
    __shared__ float attn[N * N];
    __shared__ int   cnt[NREL * N];   // 8 KB
    int tid  = threadIdx.x;
    int wave = tid >> 6, lane = tid & 63;

    // 16 waves, ~6 dots each; float4 loads (q,k are L2-resident)
    for (int p = wave; p < N * N; p += 16) {
        int i = p / N, j = p % N;
        const float4* qp = reinterpret_cast<const float4*>(q + i * D);
        const float4* kp = reinterpret_cast<const float4*>(k + j * D);
        float acc = 0.f;
#pragma unroll
        for (int it = 0; it < 4; ++it) {
            float4 qa = qp[lane + it * 64];
            float4 ka = kp[lane + it * 64];
            acc += qa.x * ka.x + qa.y * ka.y + qa.z * ka.z + qa.w * ka.w;
        }
        for (int off = 32; off; off >>= 1) acc += __shfl_down(acc, off);
        if (lane == 0) logits[p] = acc * (1.0f / 32.0f);   // 1/sqrt(1024)
    }
    __syncthreads();

    if (tid < N) {                        // row softmax
        float m = -1e30f;
        for (int j = 0; j < N; ++j) m = fmaxf(m, logits[tid * N + j]);
        float s = 0.f, e[N];
        for (int j = 0; j < N; ++j) { e[j] = expf(logits[tid * N + j] - m); s += e[j]; }
        for (int j = 0; j < N; ++j) attn[tid * N + j] = e[j] / s;
    }
    for (int i = tid; i < NREL * N; i += 1024) cnt[i] = 0;
    __syncthreads();

    if (tid < N * N) {
        int src = tid / N, dst = tid % N;
        int et  = 2 * (speaker[src] * N + speaker[dst]) + (src >= dst ? 1 : 0);
        etype_out[tid] = et;
        atomicAdd(&cnt[et * N + dst], 1);
    }
    __syncthreads();

    if (tid < N * N) {
        int dst = tid % N;
        w_e[tid] = attn[tid] / (float)cnt[etype_out[tid] * N + dst];
    }
}

// THE BIG ONE: em_part[kc][e][:] = X[src, kc*32:(kc+1)*32] @ Wrel[etype[e]][kc*32:..., :]
// grid (100, 32), block 256 (each thread: 4 contiguous cols). Non-atomic partials.
__global__ void edge_matvec_part(const float* __restrict__ X, const float* __restrict__ Wr,
                                 const int* __restrict__ etype, float* __restrict__ em_part) {
    int e   = blockIdx.x;
    int kc  = blockIdx.y;
    int src = e / N;
    int t   = etype[e];
    const float* W = Wr + (size_t)t * D * D + (size_t)kc * KLEN * D;
    const float* x = X + src * D + kc * KLEN;
    int c0 = threadIdx.x * 4;
    float4 acc = make_float4(0.f, 0.f, 0.f, 0.f);
#pragma unroll 8
    for (int k = 0; k < KLEN; ++k) {
        float  xv = x[k];
        float4 w4 = *reinterpret_cast<const float4*>(W + (size_t)k * D + c0);
        acc.x += xv * w4.x; acc.y += xv * w4.y; acc.z += xv * w4.z; acc.w += xv * w4.w;
    }
    *reinterpret_cast<float4*>(em_part + ((size_t)(kc * (N * N) + e)) * D + c0) = acc;
}

// outv[dst] = sum_src w_e * sum_kc em_part + root + bias ; agg += outv (atomic)
// grid (10), block 256, float4 per thread
__global__ void combine_agg(const float* __restrict__ em_part, const float* __restrict__ w_e,
                            const float* __restrict__ rootacc, const float* __restrict__ bias,
                            float* __restrict__ outv, float* __restrict__ agg) {
    int dst = blockIdx.x;
    int c0  = threadIdx.x * 4;
    float4 s = make_float4(0.f, 0.f, 0.f, 0.f);
    for (int src = 0; src < N; ++src) {
        int e = src * N + dst;
        float4 sum = make_float4(0.f, 0.f, 0.f, 0.f);
#pragma unroll 8
        for (int kc = 0; kc < KCH; ++kc) {
            float4 v = *reinterpret_cast<const float4*>(
                em_part + ((size_t)(kc * (N * N) + e)) * D + c0);
            sum.x += v.x; sum.y += v.y; sum.z += v.z; sum.w += v.w;
        }
        float w = w_e[e];
        s.x += w * sum.x; s.y += w * sum.y; s.z += w * sum.z; s.w += w * sum.w;
    }
    float4 rt = *reinterpret_cast<const float4*>(rootacc + dst * D + c0);
    float4 bs = *reinterpret_cast<const float4*>(bias + c0);
    float4 o  = make_float4(s.x + rt.x + bs.x, s.y + rt.y + bs.y,
                            s.z + rt.z + bs.z, s.w + rt.w + bs.w);
    *reinterpret_cast<float4*>(outv + dst * D + c0) = o;
    atomicAdd(&agg[c0 + 0], o.x);
    atomicAdd(&agg[c0 + 1], o.y);
    atomicAdd(&agg[c0 + 2], o.z);
    atomicAdd(&agg[c0 + 3], o.w);
}

// rows 0..9: x2acc[r] += outv[r] @ gcn_root_w ; row 10: aggrel += agg @ gcn_rel_w
// grid (11, 4, 8)
__global__ void final_matvec(const float* __restrict__ outv, const float* __restrict__ agg,
                             const float* __restrict__ root_w, const float* __restrict__ rel_w,
                             float* __restrict__ x2acc, float* __restrict__ aggrel) {
    int r = blockIdx.x;
    const float* x = (r < N) ? outv + r * D : agg;
    const float* W = (r < N) ? root_w : rel_w;
    float*       y = (r < N) ? x2acc + r * D : aggrel;
    matvec_body(x, W, y, blockIdx.y * 256 + threadIdx.x, blockIdx.z * 128);
}

// dout[r][0:1024] = x2acc[r] + aggrel + rel_b ; dout[r][1024:2048] = X[r]
// grid (10, 8), block 256
__global__ void final_concat(const float* __restrict__ x2acc, const float* __restrict__ aggrel,
                             const float* __restrict__ rel_b, const float* __restrict__ X,
                             float* __restrict__ dout) {
    int r = blockIdx.x, c = blockIdx.y * 256 + threadIdx.x;
    if (c < D) dout[r * 2 * D + c] = x2acc[r * D + c] + aggrel[c] + rel_b[c];
    else       dout[r * 2 * D + c] = X[r * D + (c - D)];
}

extern "C" void kernel_launch(void* const* d_in, const int* in_sizes, int n_in,
                              void* d_out, int out_size, void* d_ws, size_t ws_size,
                              hipStream_t stream) {
    const float* X          = (const float*)d_in[0];
    const int*   speaker    = (const int*)  d_in[1];
    const float* Wq         = (const float*)d_in[2];
    const float* Wk         = (const float*)d_in[3];
    const float* Wrel       = (const float*)d_in[4];
    const float* Wroot      = (const float*)d_in[5];
    const float* bias       = (const float*)d_in[6];
    const float* gcn_rel_w  = (const float*)d_in[7];
    const float* gcn_rel_b  = (const float*)d_in[8];
    const float* gcn_root_w = (const float*)d_in[9];
    float* ws   = (float*)d_ws;
    float* dout = (float*)d_out;

    float* q       = ws + OFF_Q;
    float* kbuf    = ws + OFF_K;
    float* rootacc = ws + OFF_ROOT;
    float* aggrel  = ws + OFF_AGGREL;
    float* x2acc   = ws + OFF_X2ACC;
    float* agg     = ws + OFF_AGG;
    float* outv    = ws + OFF_OUTV;
    float* w_e     = ws + OFF_WE;
    int*   etype   = (int*)(ws + OFF_ETYPE);
    float* em_part = ws + OFF_EMPART;

    // one contiguous zero for all atomic accumulators (ws not re-poisoned between replays)
    hipMemsetAsync(ws, 0, ZERO_FLOATS * sizeof(float), stream);

    dim3 blk(256);
    pre_matvec<<<dim3(3 * N, 4, 8), blk, 0, stream>>>(X, Wq, Wk, Wroot, q, kbuf, rootacc);
    attn_edges<<<1, dim3(1024), 0, stream>>>(q, kbuf, speaker, w_e, etype);

    // the ~400 MB weight-gather: 3200 blocks, non-atomic partials
    edge_matvec_part<<<dim3(N * N, KCH), blk, 0, stream>>>(X, Wrel, etype, em_part);

    combine_agg<<<dim3(N), blk, 0, stream>>>(em_part, w_e, rootacc, bias, outv, agg);
    final_matvec<<<dim3(N + 1, 4, 8), blk, 0, stream>>>(outv, agg, gcn_root_w, gcn_rel_w,
                                                        x2acc, aggrel);
    final_concat<<<dim3(N, 8), blk, 0, stream>>>(x2acc, aggrel, gcn_rel_b, X, dout);
}

// Round 4
// 130.638 us; speedup vs baseline: 1.5889x; 1.1369x over previous
//
#include <hip/hip_runtime.h>

#define N 10
#define D 1024
#define NREL 200
#define KCH 32            // k-chunks in the big edge-matvec
#define KLEN 32           // D / KCH

typedef float f32x4 __attribute__((ext_vector_type(4)));

// ---------------- workspace layout (float offsets) ----------------
// [q | k | outacc | x2acc | aggrel] are atomic accumulators -> one contiguous memset
#define OFF_Q       0                      // N*D
#define OFF_K       (OFF_Q + N*D)          // N*D
#define OFF_OUTACC  (OFF_K + N*D)          // N*D  root + bias + RGCN messages
#define OFF_X2ACC   (OFF_OUTACC + N*D)     // N*D
#define OFF_AGGREL  (OFF_X2ACC + N*D)      // D
#define ZERO_FLOATS (OFF_AGGREL + D)
#define OFF_WE      ZERO_FLOATS            // 100 (pad 128)
#define OFF_ETYPE   (OFF_WE + 128)         // 100 ints (pad 128)

// ---- generic split matvec body: y[c] += x[kb:kb+128] . W[kb:kb+128, c] ----
__device__ __forceinline__ void matvec_body(const float* __restrict__ x,
                                            const float* __restrict__ W,
                                            float* __restrict__ y,
                                            int c, int kb) {
    const float* Wp = W + (size_t)kb * D + c;
    const float* xp = x + kb;
    float acc = 0.f;
#pragma unroll 8
    for (int k = 0; k < 128; ++k) acc += xp[k] * Wp[(size_t)k * D];
    atomicAdd(&y[c], acc);
}

// rows 0..9: q[r] += X[r]@Wq ; 10..19: k[r] += X[r]@Wk ; 20..29: outacc[r] += X[r]@Wroot
// grid (30, 4, 8), block 256
__global__ void pre_matvec(const float* __restrict__ X, const float* __restrict__ Wq,
                           const float* __restrict__ Wk, const float* __restrict__ Wroot,
                           float* __restrict__ q, float* __restrict__ kout,
                           float* __restrict__ outacc) {
    int r   = blockIdx.x % N;
    int sel = blockIdx.x / N;
    const float* W = (sel == 0) ? Wq : (sel == 1) ? Wk : Wroot;
    float*       Y = (sel == 0) ? q  : (sel == 1) ? kout : outacc;
    matvec_body(X + r * D, W, Y + r * D, blockIdx.y * 256 + threadIdx.x, blockIdx.z * 128);
}

// single block, 1024 threads: logits -> softmax -> etype -> (rel,dst) counts -> w_e;
// also outacc += bias (outacc holds root by now; bias must land exactly once per call)
__global__ void attn_edges(const float* __restrict__ q, const float* __restrict__ k,
                           const int* __restrict__ speaker, const float* __restrict__ bias,
                           float* __restrict__ w_e, int* __restrict__ etype_out,
                           float* __restrict__ outacc) {
    __shared__ float logits[N * N];
    __shared__ float attn[N * N];
    __shared__ int   cnt[NREL * N];   // 8 KB
    int tid  = threadIdx.x;
    int wave = tid >> 6, lane = tid & 63;

    for (int p = wave; p < N * N; p += 16) {
        int i = p / N, j = p % N;
        const f32x4* qp = reinterpret_cast<const f32x4*>(q + i * D);
        const f32x4* kp = reinterpret_cast<const f32x4*>(k + j * D);
        float acc = 0.f;
#pragma unroll
        for (int it = 0; it < 4; ++it) {
            f32x4 qa = qp[lane + it * 64];
            f32x4 ka = kp[lane + it * 64];
            acc += qa.x * ka.x + qa.y * ka.y + qa.z * ka.z + qa.w * ka.w;
        }
        for (int off = 32; off; off >>= 1) acc += __shfl_down(acc, off);
        if (lane == 0) logits[p] = acc * (1.0f / 32.0f);   // 1/sqrt(1024)
    }
    // bias add (independent of attn math; outacc == root here, pre_matvec already done)
    for (int i = tid; i < N * D; i += 1024) outacc[i] += bias[i & (D - 1)];
    __syncthreads();

    if (tid < N) {                        // row softmax
        float m = -1e30f;
        for (int j = 0; j < N; ++j) m = fmaxf(m, logits[tid * N + j]);
        float s = 0.f, e[N];
        for (int j = 0; j < N; ++j) { e[j] = expf(logits[tid * N + j] - m); s += e[j]; }
        for (int j = 0; j < N; ++j) attn[tid * N + j] = e[j] / s;
    }
    for (int i = tid; i < NREL * N; i += 1024) cnt[i] = 0;
    __syncthreads();

    if (tid < N * N) {
        int src = tid / N, dst = tid % N;
        int et  = 2 * (speaker[src] * N + speaker[dst]) + (src >= dst ? 1 : 0);
        etype_out[tid] = et;
        atomicAdd(&cnt[et * N + dst], 1);
    }
    __syncthreads();

    if (tid < N * N) {
        int dst = tid % N;
        w_e[tid] = attn[tid] / (float)cnt[etype_out[tid] * N + dst];
    }
}

// THE BIG ONE: outacc[dst] += w_e[e] * (X[src, kcslice] @ Wrel[etype[e]][kcslice, :])
// grid (100, 32), block 256 (4 cols/thread). NT loads on the zero-reuse weights;
// direct atomics into the 40 KB outacc (320 adds/address spread over ~70 us).
__global__ void edge_matvec(const float* __restrict__ X, const float* __restrict__ Wr,
                            const float* __restrict__ w_e, const int* __restrict__ etype,
                            float* __restrict__ outacc) {
    int e   = blockIdx.x;
    int kc  = blockIdx.y;
    int src = e / N, dst = e % N;
    int t   = etype[e];
    float we = w_e[e];
    const float* W = Wr + (size_t)t * D * D + (size_t)kc * KLEN * D;
    const float* x = X + src * D + kc * KLEN;
    int c0 = threadIdx.x * 4;
    f32x4 acc = 0.f;
#pragma unroll 8
    for (int k = 0; k < KLEN; ++k) {
        f32x4 w4 = __builtin_nontemporal_load(
            reinterpret_cast<const f32x4*>(W + (size_t)k * D + c0));
        acc += x[k] * w4;
    }
    float* o = outacc + dst * D + c0;
    atomicAdd(o + 0, we * acc.x);
    atomicAdd(o + 1, we * acc.y);
    atomicAdd(o + 2, we * acc.z);
    atomicAdd(o + 3, we * acc.w);
}

// rows 0..9: x2acc[r] += outacc[r] @ gcn_root_w ; row 10: aggrel += (sum_r outacc[r]) @ gcn_rel_w
// agg row-sum computed on the fly into LDS. grid (11, 4, 8), block 256
__global__ void final_matvec(const float* __restrict__ outacc,
                             const float* __restrict__ root_w, const float* __restrict__ rel_w,
                             float* __restrict__ x2acc, float* __restrict__ aggrel) {
    __shared__ float xs[128];
    int r  = blockIdx.x;
    int c  = blockIdx.y * 256 + threadIdx.x;
    int kb = blockIdx.z * 128;
    if (threadIdx.x < 128) {
        if (r < N) {
            xs[threadIdx.x] = outacc[r * D + kb + threadIdx.x];
        } else {
            float s = 0.f;
#pragma unroll
            for (int rr = 0; rr < N; ++rr) s += outacc[rr * D + kb + threadIdx.x];
            xs[threadIdx.x] = s;
        }
    }
    __syncthreads();
    const float* W = (r < N) ? root_w : rel_w;
    float*       y = (r < N) ? x2acc + r * D : aggrel;
    const float* Wp = W + (size_t)kb * D + c;
    float acc = 0.f;
#pragma unroll 8
    for (int k = 0; k < 128; ++k) acc += xs[k] * Wp[(size_t)k * D];
    atomicAdd(&y[c], acc);
}

// dout[r][0:1024] = x2acc[r] + aggrel + rel_b ; dout[r][1024:2048] = X[r]
// grid (10, 8), block 256
__global__ void final_concat(const float* __restrict__ x2acc, const float* __restrict__ aggrel,
                             const float* __restrict__ rel_b, const float* __restrict__ X,
                             float* __restrict__ dout) {
    int r = blockIdx.x, c = blockIdx.y * 256 + threadIdx.x;
    if (c < D) dout[r * 2 * D + c] = x2acc[r * D + c] + aggrel[c] + rel_b[c];
    else       dout[r * 2 * D + c] = X[r * D + (c - D)];
}

extern "C" void kernel_launch(void* const* d_in, const int* in_sizes, int n_in,
                              void* d_out, int out_size, void* d_ws, size_t ws_size,
                              hipStream_t stream) {
    const float* X          = (const float*)d_in[0];
    const int*   speaker    = (const int*)  d_in[1];
    const float* Wq         = (const float*)d_in[2];
    const float* Wk         = (const float*)d_in[3];
    const float* Wrel       = (const float*)d_in[4];
    const float* Wroot      = (const float*)d_in[5];
    const float* bias       = (const float*)d_in[6];
    const float* gcn_rel_w  = (const float*)d_in[7];
    const float* gcn_rel_b  = (const float*)d_in[8];
    const float* gcn_root_w = (const float*)d_in[9];
    float* ws   = (float*)d_ws;
    float* dout = (float*)d_out;

    float* q      = ws + OFF_Q;
    float* kbuf   = ws + OFF_K;
    float* outacc = ws + OFF_OUTACC;
    float* x2acc  = ws + OFF_X2ACC;
    float* aggrel = ws + OFF_AGGREL;
    float* w_e    = ws + OFF_WE;
    int*   etype  = (int*)(ws + OFF_ETYPE);

    // one contiguous zero for all atomic accumulators (ws not re-poisoned between replays)
    hipMemsetAsync(ws, 0, ZERO_FLOATS * sizeof(float), stream);

    dim3 blk(256);
    pre_matvec<<<dim3(3 * N, 4, 8), blk, 0, stream>>>(X, Wq, Wk, Wroot, q, kbuf, outacc);
    attn_edges<<<1, dim3(1024), 0, stream>>>(q, kbuf, speaker, bias, w_e, etype, outacc);

    // the ~400 MB weight-gather, fused with w_e scaling and dst-scatter
    edge_matvec<<<dim3(N * N, KCH), blk, 0, stream>>>(X, Wrel, w_e, etype, outacc);

    final_matvec<<<dim3(N + 1, 4, 8), blk, 0, stream>>>(outacc, gcn_root_w, gcn_rel_w,
                                                        x2acc, aggrel);
    final_concat<<<dim3(N, 8), blk, 0, stream>>>(x2acc, aggrel, gcn_rel_b, X, dout);
}

// Round 6
// 128.646 us; speedup vs baseline: 1.6135x; 1.0155x over previous
//
#include <hip/hip_runtime.h>

#define N 10
#define D 1024
#define NREL 200
#define KCH 32            // k-slices in the gather (each KLEN rows)
#define KLEN 32           // D / KCH
#define MAXG 8            // max edges per gather group (register-blocked)

typedef float f32x4 __attribute__((ext_vector_type(4)));

// ---------------- workspace layout (float offsets) ----------------
// [q | k | root | x2acc | aggrel | em] zeroed each call -> one contiguous memset
#define OFF_Q       0                      // N*D
#define OFF_K       (OFF_Q + N*D)          // N*D
#define OFF_ROOT    (OFF_K + N*D)          // N*D
#define OFF_X2ACC   (OFF_ROOT + N*D)       // N*D
#define OFF_AGGREL  (OFF_X2ACC + N*D)      // D
#define OFF_EM      (OFF_AGGREL + D)       // N*N*D  unscaled per-edge messages
#define ZERO_FLOATS (OFF_EM + N*N*D)
#define OFF_WE      ZERO_FLOATS            // 100 (pad 128)
#define OFF_NITEMS  (OFF_WE + 128)         // 1 int (pad 16)
#define OFF_ITEMS   (OFF_NITEMS + 16)      // 100 items x 10 ints: {etype, gsize, e0..e7}

// ---- build etype groups from speaker only (no attention dependency) ----
__global__ void build_groups(const int* __restrict__ speaker, int* __restrict__ n_items,
                             int* __restrict__ items) {
    __shared__ int sp[N];
    __shared__ int gcnt[NREL];
    __shared__ int ibase[NREL];
    int tid = threadIdx.x;
    if (tid < N) sp[tid] = speaker[tid];
    __syncthreads();
    if (tid < NREL) {
        int c = 0;
        for (int e = 0; e < N * N; ++e) {
            int src = e / N, dst = e % N;
            int et = 2 * (sp[src] * N + sp[dst]) + (src >= dst ? 1 : 0);
            c += (et == tid);
        }
        gcnt[tid] = c;
    }
    __syncthreads();
    if (tid == 0) {
        int b = 0;
        for (int t = 0; t < NREL; ++t) { ibase[t] = b; b += (gcnt[t] + MAXG - 1) / MAXG; }
        *n_items = b;
    }
    __syncthreads();
    if (tid < NREL && gcnt[tid] > 0) {
        int it = ibase[tid], slot = 0;
        int* rec = items + it * 10;
        for (int e = 0; e < N * N; ++e) {
            int src = e / N, dst = e % N;
            int et = 2 * (sp[src] * N + sp[dst]) + (src >= dst ? 1 : 0);
            if (et != tid) continue;
            if (slot == 0) rec[0] = tid;
            rec[2 + slot] = e;
            if (++slot == MAXG) { rec[1] = MAXG; ++it; rec = items + it * 10; slot = 0; }
        }
        if (slot > 0) { rec[1] = slot; for (int g = slot; g < MAXG; ++g) rec[2 + g] = -1; }
    }
}

// ---- ONE dispatch: [bx<100] etype-grouped weight-gather -> em (unscaled)
//      [bx>=100] q/k/root pre-matvecs (X staged in LDS, all 10 rows per W tile)
__global__ void big_fused(const float* __restrict__ X, const float* __restrict__ Wrel,
                          const int* __restrict__ n_items, const int* __restrict__ items,
                          const float* __restrict__ Wq, const float* __restrict__ Wk,
                          const float* __restrict__ Wroot,
                          float* __restrict__ q, float* __restrict__ kout,
                          float* __restrict__ rootacc, float* __restrict__ em) {
    int bx = blockIdx.x, by = blockIdx.y, tid = threadIdx.x;
    if (bx < 100) {
        if (bx >= *n_items) return;        // block-uniform early exit (before any barrier)
        __shared__ int   meta[10];
        __shared__ float xs[MAXG][KLEN];
        if (tid < 10) meta[tid] = items[bx * 10 + tid];
        __syncthreads();
        int t = meta[0], gsize = meta[1];
        {   // stage x slices (zero-padded for g>=gsize so the unrolled FMAs are inert)
            int g = tid >> 5, k = tid & 31;            // 256 threads == MAXG*KLEN
            int e = meta[2 + g];
            xs[g][k] = (g < gsize) ? X[(e / N) * D + by * KLEN + k] : 0.f;
        }
        __syncthreads();
        int c0 = tid * 4;
        const float* W = Wrel + (size_t)t * D * D + (size_t)by * KLEN * D;
        f32x4 acc[MAXG];
#pragma unroll
        for (int g = 0; g < MAXG; ++g) acc[g] = 0.f;
#pragma unroll 4
        for (int k = 0; k < KLEN; ++k) {
            f32x4 w4 = __builtin_nontemporal_load(
                reinterpret_cast<const f32x4*>(W + (size_t)k * D + c0));
#pragma unroll
            for (int g = 0; g < MAXG; ++g) acc[g] += xs[g][k] * w4;
        }
        for (int g = 0; g < gsize; ++g) {
            float* o = em + (size_t)meta[2 + g] * D + c0;
            atomicAdd(o + 0, acc[g].x);
            atomicAdd(o + 1, acc[g].y);
            atomicAdd(o + 2, acc[g].z);
            atomicAdd(o + 3, acc[g].w);
        }
    } else {
        int sel = bx - 100;                 // 0:Wq 1:Wk 2:Wroot
        int kb  = (by & 7) * 128;
        int c   = (by >> 3) * 256 + tid;
        const float* W = (sel == 0) ? Wq : (sel == 1) ? Wk : Wroot;
        float*       Y = (sel == 0) ? q  : (sel == 1) ? kout : rootacc;
        __shared__ float xs2[N][128];
        for (int idx = tid; idx < N * 128; idx += 256) {
            int r = idx >> 7, k = idx & 127;
            xs2[r][k] = X[r * D + kb + k];
        }
        __syncthreads();
        float acc[N];
#pragma unroll
        for (int r = 0; r < N; ++r) acc[r] = 0.f;
#pragma unroll 4
        for (int k = 0; k < 128; ++k) {
            float w = W[(size_t)(kb + k) * D + c];
#pragma unroll
            for (int r = 0; r < N; ++r) acc[r] += xs2[r][k] * w;
        }
#pragma unroll
        for (int r = 0; r < N; ++r) atomicAdd(&Y[r * D + c], acc[r]);
    }
}

// ---- single block, 1024 threads: logits -> softmax -> (rel,dst)-mean -> w_e ----
// ALL __syncthreads() at top level (R5 bug: a barrier inside the tid<100 branch
// split wave 1 across both paths -> UB -> racy attn/cnt reads).
__global__ void attn_edges(const float* __restrict__ q, const float* __restrict__ k,
                           const int* __restrict__ speaker, float* __restrict__ w_e) {
    __shared__ float logits[N * N];
    __shared__ float attn[N * N];
    __shared__ int   cnt[NREL * N];   // 8 KB
    int tid  = threadIdx.x;
    int wave = tid >> 6, lane = tid & 63;

    for (int p = wave; p < N * N; p += 16) {
        int i = p / N, j = p % N;
        const f32x4* qp = reinterpret_cast<const f32x4*>(q + i * D);
        const f32x4* kp = reinterpret_cast<const f32x4*>(k + j * D);
        float acc = 0.f;
#pragma unroll
        for (int it = 0; it < 4; ++it) {
            f32x4 qa = qp[lane + it * 64];
            f32x4 ka = kp[lane + it * 64];
            acc += qa.x * ka.x + qa.y * ka.y + qa.z * ka.z + qa.w * ka.w;
        }
        for (int off = 32; off; off >>= 1) acc += __shfl_down(acc, off);
        if (lane == 0) logits[p] = acc * (1.0f / 32.0f);   // 1/sqrt(1024)
    }
    __syncthreads();

    if (tid < N) {                        // row softmax
        float m = -1e30f;
        for (int j = 0; j < N; ++j) m = fmaxf(m, logits[tid * N + j]);
        float s = 0.f, e[N];
        for (int j = 0; j < N; ++j) { e[j] = expf(logits[tid * N + j] - m); s += e[j]; }
        for (int j = 0; j < N; ++j) attn[tid * N + j] = e[j] / s;
    }
    for (int i = tid; i < NREL * N; i += 1024) cnt[i] = 0;
    __syncthreads();          // attn visible + cnt zeroed

    int et = 0;
    if (tid < N * N) {
        int src = tid / N, dst = tid % N;
        et = 2 * (speaker[src] * N + speaker[dst]) + (src >= dst ? 1 : 0);
        atomicAdd(&cnt[et * N + dst], 1);
    }
    __syncthreads();          // counts complete (uniform barrier)

    if (tid < N * N) {
        w_e[tid] = attn[tid] / (float)cnt[et * N + (tid % N)];
    }
}

// ---- combine em*w_e + root + bias on the fly, then second-layer matvec ----
// rows 0..9: x2acc[r] += out[r] @ gcn_root_w ; row 10: aggrel += (sum_r out[r]) @ gcn_rel_w
// grid (11, 4, 8), block 256
__global__ void combine_final(const float* __restrict__ em, const float* __restrict__ w_e,
                              const float* __restrict__ rootacc, const float* __restrict__ bias,
                              const float* __restrict__ root_w, const float* __restrict__ rel_w,
                              float* __restrict__ x2acc, float* __restrict__ aggrel) {
    __shared__ float wes[N * N];
    __shared__ float xs[128];
    int r   = blockIdx.x;
    int tid = threadIdx.x;
    int c   = blockIdx.y * 256 + tid;
    int kb  = blockIdx.z * 128;
    if (tid < N * N) wes[tid] = w_e[tid];
    __syncthreads();
    if (tid < 128) {
        int j = kb + tid;
        float v;
        if (r < N) {
            v = rootacc[r * D + j] + bias[j];
#pragma unroll
            for (int src = 0; src < N; ++src) {
                int e = src * N + r;
                v += wes[e] * em[(size_t)e * D + j];
            }
        } else {
            v = (float)N * bias[j];
#pragma unroll
            for (int rr = 0; rr < N; ++rr) v += rootacc[rr * D + j];
            for (int e = 0; e < N * N; ++e) v += wes[e] * em[(size_t)e * D + j];
        }
        xs[tid] = v;
    }
    __syncthreads();
    const float* W = (r < N) ? root_w : rel_w;
    float*       y = (r < N) ? x2acc + r * D : aggrel;
    const float* Wp = W + (size_t)kb * D + c;
    float acc = 0.f;
#pragma unroll 8
    for (int k = 0; k < 128; ++k) acc += xs[k] * Wp[(size_t)k * D];
    atomicAdd(&y[c], acc);
}

// dout[r][0:1024] = x2acc[r] + aggrel + rel_b ; dout[r][1024:2048] = X[r]
// grid (10, 8), block 256
__global__ void final_concat(const float* __restrict__ x2acc, const float* __restrict__ aggrel,
                             const float* __restrict__ rel_b, const float* __restrict__ X,
                             float* __restrict__ dout) {
    int r = blockIdx.x, c = blockIdx.y * 256 + threadIdx.x;
    if (c < D) dout[r * 2 * D + c] = x2acc[r * D + c] + aggrel[c] + rel_b[c];
    else       dout[r * 2 * D + c] = X[r * D + (c - D)];
}

extern "C" void kernel_launch(void* const* d_in, const int* in_sizes, int n_in,
                              void* d_out, int out_size, void* d_ws, size_t ws_size,
                              hipStream_t stream) {
    const float* X          = (const float*)d_in[0];
    const int*   speaker    = (const int*)  d_in[1];
    const float* Wq         = (const float*)d_in[2];
    const float* Wk         = (const float*)d_in[3];
    const float* Wrel       = (const float*)d_in[4];
    const float* Wroot      = (const float*)d_in[5];
    const float* bias       = (const float*)d_in[6];
    const float* gcn_rel_w  = (const float*)d_in[7];
    const float* gcn_rel_b  = (const float*)d_in[8];
    const float* gcn_root_w = (const float*)d_in[9];
    float* ws   = (float*)d_ws;
    float* dout = (float*)d_out;

    float* q       = ws + OFF_Q;
    float* kbuf    = ws + OFF_K;
    float* rootacc = ws + OFF_ROOT;
    float* x2acc   = ws + OFF_X2ACC;
    float* aggrel  = ws + OFF_AGGREL;
    float* em      = ws + OFF_EM;
    float* w_e     = ws + OFF_WE;
    int*   nitems  = (int*)(ws + OFF_NITEMS);
    int*   items   = (int*)(ws + OFF_ITEMS);

    // zero all accumulators (ws not re-poisoned between replays; re-zero every call)
    hipMemsetAsync(ws, 0, ZERO_FLOATS * sizeof(float), stream);

    dim3 blk(256);
    build_groups<<<1, blk, 0, stream>>>(speaker, nitems, items);

    // gather (dedup'd, ~n_items*4MB) + q/k/root matvecs in ONE dispatch
    big_fused<<<dim3(103, KCH), blk, 0, stream>>>(X, Wrel, nitems, items, Wq, Wk, Wroot,
                                                  q, kbuf, rootacc, em);

    attn_edges<<<1, dim3(1024), 0, stream>>>(q, kbuf, speaker, w_e);
    combine_final<<<dim3(N + 1, 4, 8), blk, 0, stream>>>(em, w_e, rootacc, bias,
                                                         gcn_root_w, gcn_rel_w, x2acc, aggrel);
    final_concat<<<dim3(N, 8), blk, 0, stream>>>(x2acc, aggrel, gcn_rel_b, X, dout);
}

// Round 7
// 111.008 us; speedup vs baseline: 1.8699x; 1.1589x over previous
//
#include <hip/hip_runtime.h>

#define N 10
#define D 1024
#define NREL 200
#define KCH 32            // k-slices in the gather (each KLEN rows)
#define KLEN 32           // D / KCH
#define MAXG 8            // max edges per gather group (register-blocked)

typedef float f32x4 __attribute__((ext_vector_type(4)));

// ---------------- workspace layout (float offsets) ----------------
// zeroed each call: [q | k | root | x2acc | aggrel]  (atomic accumulators only)
#define OFF_Q       0                      // N*D
#define OFF_K       (OFF_Q + N*D)          // N*D
#define OFF_ROOT    (OFF_K + N*D)          // N*D
#define OFF_X2ACC   (OFF_ROOT + N*D)       // N*D
#define OFF_AGGREL  (OFF_X2ACC + N*D)      // D
#define ZERO_FLOATS (OFF_AGGREL + D)
#define OFF_EM      ZERO_FLOATS            // N*N*D   (fully overwritten by reduce_em)
#define OFF_WE      (OFF_EM + N*N*D)       // 100 (pad 128)
#define OFF_NITEMS  (OFF_WE + 128)         // 1 int (pad 16)
#define OFF_ITEMS   (OFF_NITEMS + 16)      // 100 items x 10 ints: {etype, gsize, e0..e7}
#define OFF_EMPART  (OFF_ITEMS + 1024)     // KCH*N*N*D floats (13.1 MB, fully overwritten)

// ---- build etype groups from speaker only (no attention dependency) ----
__global__ void build_groups(const int* __restrict__ speaker, int* __restrict__ n_items,
                             int* __restrict__ items) {
    __shared__ int sp[N];
    __shared__ int gcnt[NREL];
    __shared__ int ibase[NREL];
    int tid = threadIdx.x;
    if (tid < N) sp[tid] = speaker[tid];
    __syncthreads();
    if (tid < NREL) {
        int c = 0;
        for (int e = 0; e < N * N; ++e) {
            int src = e / N, dst = e % N;
            int et = 2 * (sp[src] * N + sp[dst]) + (src >= dst ? 1 : 0);
            c += (et == tid);
        }
        gcnt[tid] = c;
    }
    __syncthreads();
    if (tid == 0) {
        int b = 0;
        for (int t = 0; t < NREL; ++t) { ibase[t] = b; b += (gcnt[t] + MAXG - 1) / MAXG; }
        *n_items = b;
    }
    __syncthreads();
    if (tid < NREL && gcnt[tid] > 0) {
        int it = ibase[tid], slot = 0;
        int* rec = items + it * 10;
        for (int e = 0; e < N * N; ++e) {
            int src = e / N, dst = e % N;
            int et = 2 * (sp[src] * N + sp[dst]) + (src >= dst ? 1 : 0);
            if (et != tid) continue;
            if (slot == 0) rec[0] = tid;
            rec[2 + slot] = e;
            if (++slot == MAXG) { rec[1] = MAXG; ++it; rec = items + it * 10; slot = 0; }
        }
        if (slot > 0) { rec[1] = slot; for (int g = slot; g < MAXG; ++g) rec[2 + g] = -1; }
    }
}

// ---- ONE dispatch: [bx<100] etype-grouped weight-gather -> em_part (plain stores,
//      NO atomics, NO nontemporal)   [bx>=100] q/k/root pre-matvecs
__global__ void big_fused(const float* __restrict__ X, const float* __restrict__ Wrel,
                          const int* __restrict__ n_items, const int* __restrict__ items,
                          const float* __restrict__ Wq, const float* __restrict__ Wk,
                          const float* __restrict__ Wroot,
                          float* __restrict__ q, float* __restrict__ kout,
                          float* __restrict__ rootacc, float* __restrict__ em_part) {
    int bx = blockIdx.x, by = blockIdx.y, tid = threadIdx.x;
    if (bx < 100) {
        if (bx >= *n_items) return;        // block-uniform early exit (before any barrier)
        __shared__ int   meta[10];
        __shared__ float xs[MAXG][KLEN];
        if (tid < 10) meta[tid] = items[bx * 10 + tid];
        __syncthreads();
        int t = meta[0], gsize = meta[1];
        {   // stage x slices (zero-padded for g>=gsize so the unrolled FMAs are inert)
            int g = tid >> 5, k = tid & 31;            // 256 threads == MAXG*KLEN
            int e = meta[2 + g];
            xs[g][k] = (g < gsize) ? X[(e / N) * D + by * KLEN + k] : 0.f;
        }
        __syncthreads();
        int c0 = tid * 4;
        const float* W = Wrel + (size_t)t * D * D + (size_t)by * KLEN * D;
        f32x4 acc[MAXG];
#pragma unroll
        for (int g = 0; g < MAXG; ++g) acc[g] = 0.f;
#pragma unroll 4
        for (int k = 0; k < KLEN; ++k) {
            f32x4 w4 = *reinterpret_cast<const f32x4*>(W + (size_t)k * D + c0);
#pragma unroll
            for (int g = 0; g < MAXG; ++g) acc[g] += xs[g][k] * w4;
        }
        // plain stores: element (by, e, c) owned exclusively by this block
        for (int g = 0; g < gsize; ++g) {
            *reinterpret_cast<f32x4*>(
                em_part + ((size_t)(by * (N * N) + meta[2 + g])) * D + c0) = acc[g];
        }
    } else {
        int sel = bx - 100;                 // 0:Wq 1:Wk 2:Wroot
        int kb  = (by & 7) * 128;
        int c   = (by >> 3) * 256 + tid;
        const float* W = (sel == 0) ? Wq : (sel == 1) ? Wk : Wroot;
        float*       Y = (sel == 0) ? q  : (sel == 1) ? kout : rootacc;
        __shared__ float xs2[N][128];
        for (int idx = tid; idx < N * 128; idx += 256) {
            int r = idx >> 7, k = idx & 127;
            xs2[r][k] = X[r * D + kb + k];
        }
        __syncthreads();
        float acc[N];
#pragma unroll
        for (int r = 0; r < N; ++r) acc[r] = 0.f;
#pragma unroll 4
        for (int k = 0; k < 128; ++k) {
            float w = W[(size_t)(kb + k) * D + c];
#pragma unroll
            for (int r = 0; r < N; ++r) acc[r] += xs2[r][k] * w;
        }
#pragma unroll
        for (int r = 0; r < N; ++r) atomicAdd(&Y[r * D + c], acc[r]);
    }
}

// ---- em[e][c] = sum_by em_part[by][e][c] ; grid (100, 8), block 256 ----
// 256 threads = 2 by-halves x 128 cols; LDS pair-reduce; plain store (no atomics)
__global__ void reduce_em(const float* __restrict__ em_part, float* __restrict__ em) {
    __shared__ float ps[2][128];
    int e  = blockIdx.x;
    int c  = blockIdx.y * 128 + (threadIdx.x & 127);
    int h  = threadIdx.x >> 7;           // by-half: 0 -> by 0..15, 1 -> by 16..31
    float s = 0.f;
#pragma unroll
    for (int i = 0; i < KCH / 2; ++i) {
        int by = h * (KCH / 2) + i;
        s += em_part[((size_t)(by * (N * N) + e)) * D + c];
    }
    ps[h][threadIdx.x & 127] = s;
    __syncthreads();
    if (threadIdx.x < 128) em[(size_t)e * D + c] = ps[0][threadIdx.x] + ps[1][threadIdx.x];
}

// ---- single block, 1024 threads: logits -> softmax -> (rel,dst)-mean -> w_e ----
// ALL __syncthreads() at top level (uniform).
__global__ void attn_edges(const float* __restrict__ q, const float* __restrict__ k,
                           const int* __restrict__ speaker, float* __restrict__ w_e) {
    __shared__ float logits[N * N];
    __shared__ float attn[N * N];
    __shared__ int   cnt[NREL * N];   // 8 KB
    int tid  = threadIdx.x;
    int wave = tid >> 6, lane = tid & 63;

    for (int p = wave; p < N * N; p += 16) {
        int i = p / N, j = p % N;
        const f32x4* qp = reinterpret_cast<const f32x4*>(q + i * D);
        const f32x4* kp = reinterpret_cast<const f32x4*>(k + j * D);
        float acc = 0.f;
#pragma unroll
        for (int it = 0; it < 4; ++it) {
            f32x4 qa = qp[lane + it * 64];
            f32x4 ka = kp[lane + it * 64];
            acc += qa.x * ka.x + qa.y * ka.y + qa.z * ka.z + qa.w * ka.w;
        }
        for (int off = 32; off; off >>= 1) acc += __shfl_down(acc, off);
        if (lane == 0) logits[p] = acc * (1.0f / 32.0f);   // 1/sqrt(1024)
    }
    __syncthreads();

    if (tid < N) {                        // row softmax
        float m = -1e30f;
        for (int j = 0; j < N; ++j) m = fmaxf(m, logits[tid * N + j]);
        float s = 0.f, e[N];
        for (int j = 0; j < N; ++j) { e[j] = expf(logits[tid * N + j] - m); s += e[j]; }
        for (int j = 0; j < N; ++j) attn[tid * N + j] = e[j] / s;
    }
    for (int i = tid; i < NREL * N; i += 1024) cnt[i] = 0;
    __syncthreads();          // attn visible + cnt zeroed

    int et = 0;
    if (tid < N * N) {
        int src = tid / N, dst = tid % N;
        et = 2 * (speaker[src] * N + speaker[dst]) + (src >= dst ? 1 : 0);
        atomicAdd(&cnt[et * N + dst], 1);
    }
    __syncthreads();          // counts complete (uniform barrier)

    if (tid < N * N) {
        w_e[tid] = attn[tid] / (float)cnt[et * N + (tid % N)];
    }
}

// ---- combine em*w_e + root + bias on the fly, then second-layer matvec ----
// rows 0..9: x2acc[r] += out[r] @ gcn_root_w ; row 10: aggrel += (sum_r out[r]) @ gcn_rel_w
// grid (11, 4, 8), block 256
__global__ void combine_final(const float* __restrict__ em, const float* __restrict__ w_e,
                              const float* __restrict__ rootacc, const float* __restrict__ bias,
                              const float* __restrict__ root_w, const float* __restrict__ rel_w,
                              float* __restrict__ x2acc, float* __restrict__ aggrel) {
    __shared__ float wes[N * N];
    __shared__ float xs[128];
    int r   = blockIdx.x;
    int tid = threadIdx.x;
    int c   = blockIdx.y * 256 + tid;
    int kb  = blockIdx.z * 128;
    if (tid < N * N) wes[tid] = w_e[tid];
    __syncthreads();
    if (tid < 128) {
        int j = kb + tid;
        float v;
        if (r < N) {
            v = rootacc[r * D + j] + bias[j];
#pragma unroll
            for (int src = 0; src < N; ++src) {
                int e = src * N + r;
                v += wes[e] * em[(size_t)e * D + j];
            }
        } else {
            v = (float)N * bias[j];
#pragma unroll
            for (int rr = 0; rr < N; ++rr) v += rootacc[rr * D + j];
            for (int e = 0; e < N * N; ++e) v += wes[e] * em[(size_t)e * D + j];
        }
        xs[tid] = v;
    }
    __syncthreads();
    const float* W = (r < N) ? root_w : rel_w;
    float*       y = (r < N) ? x2acc + r * D : aggrel;
    const float* Wp = W + (size_t)kb * D + c;
    float acc = 0.f;
#pragma unroll 8
    for (int k = 0; k < 128; ++k) acc += xs[k] * Wp[(size_t)k * D];
    atomicAdd(&y[c], acc);
}

// dout[r][0:1024] = x2acc[r] + aggrel + rel_b ; dout[r][1024:2048] = X[r]
// grid (10, 8), block 256
__global__ void final_concat(const float* __restrict__ x2acc, const float* __restrict__ aggrel,
                             const float* __restrict__ rel_b, const float* __restrict__ X,
                             float* __restrict__ dout) {
    int r = blockIdx.x, c = blockIdx.y * 256 + threadIdx.x;
    if (c < D) dout[r * 2 * D + c] = x2acc[r * D + c] + aggrel[c] + rel_b[c];
    else       dout[r * 2 * D + c] = X[r * D + (c - D)];
}

extern "C" void kernel_launch(void* const* d_in, const int* in_sizes, int n_in,
                              void* d_out, int out_size, void* d_ws, size_t ws_size,
                              hipStream_t stream) {
    const float* X          = (const float*)d_in[0];
    const int*   speaker    = (const int*)  d_in[1];
    const float* Wq         = (const float*)d_in[2];
    const float* Wk         = (const float*)d_in[3];
    const float* Wrel       = (const float*)d_in[4];
    const float* Wroot      = (const float*)d_in[5];
    const float* bias       = (const float*)d_in[6];
    const float* gcn_rel_w  = (const float*)d_in[7];
    const float* gcn_rel_b  = (const float*)d_in[8];
    const float* gcn_root_w = (const float*)d_in[9];
    float* ws   = (float*)d_ws;
    float* dout = (float*)d_out;

    float* q       = ws + OFF_Q;
    float* kbuf    = ws + OFF_K;
    float* rootacc = ws + OFF_ROOT;
    float* x2acc   = ws + OFF_X2ACC;
    float* aggrel  = ws + OFF_AGGREL;
    float* em      = ws + OFF_EM;
    float* w_e     = ws + OFF_WE;
    int*   nitems  = (int*)(ws + OFF_NITEMS);
    int*   items   = (int*)(ws + OFF_ITEMS);
    float* em_part = ws + OFF_EMPART;

    // zero only the atomic accumulators (168 KB); em/em_part are fully overwritten
    hipMemsetAsync(ws, 0, ZERO_FLOATS * sizeof(float), stream);

    dim3 blk(256);
    build_groups<<<1, blk, 0, stream>>>(speaker, nitems, items);

    // gather (dedup'd, ~n_items*4MB, plain loads+stores) + q/k/root matvecs
    big_fused<<<dim3(103, KCH), blk, 0, stream>>>(X, Wrel, nitems, items, Wq, Wk, Wroot,
                                                  q, kbuf, rootacc, em_part);

    attn_edges<<<1, dim3(1024), 0, stream>>>(q, kbuf, speaker, w_e);
    reduce_em<<<dim3(N * N, 8), blk, 0, stream>>>(em_part, em);
    combine_final<<<dim3(N + 1, 4, 8), blk, 0, stream>>>(em, w_e, rootacc, bias,
                                                         gcn_root_w, gcn_rel_w, x2acc, aggrel);
    final_concat<<<dim3(N, 8), blk, 0, stream>>>(x2acc, aggrel, gcn_rel_b, X, dout);
}